// Round 6
// baseline (711.329 us; speedup 1.0000x reference)
//
#include <hip/hip_runtime.h>

#define B_ 2048
#define T_ 2048
#define SPW 16    // samples per block (MFMA N dimension)
#define GSTR 162  // per-g word stride in exchange buf (16 samples * 10 + 2 pad)

typedef _Float16 f16x8 __attribute__((ext_vector_type(8)));
typedef float    f32x4 __attribute__((ext_vector_type(4)));
typedef unsigned u32x2 __attribute__((ext_vector_type(2)));
typedef unsigned u32x4 __attribute__((ext_vector_type(4)));

__device__ __forceinline__ unsigned pkrtz(float lo, float hi) {
    return __builtin_bit_cast(unsigned, __builtin_amdgcn_cvt_pkrtz(lo, hi));
}

// Barrier that waits ONLY on LDS (lgkmcnt), not vmcnt: __syncthreads drains
// vmcnt(0) too (m97 lesson), which serialized our x prefetch into the
// recurrence once per 4 steps. LDS ordering needs only lgkmcnt; x loads are
// lane-private, so skipping the vmcnt drain is safe. (m201-verified pair.)
__device__ __forceinline__ void lds_barrier() {
    asm volatile("s_waitcnt lgkmcnt(0)" ::: "memory");
    __builtin_amdgcn_s_barrier();
}

// Round 6: round-5 structure (4 waves, wave w = tile w, lane-aligned f16
// h-exchange, double-buffered, one barrier/step) with the serial path cut:
//  - lds_barrier() instead of __syncthreads(): no per-step vmcnt(0) drain,
//    so the float4 x prefetch latency hides across its 4-step slack.
//  - parallel MFMAs (independent, C=ci / C=0) + f32 add, removing one
//    dependent-MFMA latency from the path.
//  - h-independent ci affine computed between publish-write and barrier.
//  - exchange reads forced to 2x ds_read_b128.
__global__ __launch_bounds__(256)
void rnn_mfma_4w2(
    const float* __restrict__ x, const float* __restrict__ W_ih,
    const float* __restrict__ W_hh, const float* __restrict__ b_ih,
    const float* __restrict__ b_hh, const float* __restrict__ W_fc,
    const float* __restrict__ b_fc, float* __restrict__ out)
{
    __shared__ __align__(16) unsigned ex[2][4 * GSTR];  // [buf][g][s][10 words]
    __shared__ float fcb[4][SPW];

    const int tid = threadIdx.x;
    const int w = tid >> 6;          // wave index == tile index (rows 16w+..)
    const int l = tid & 63;
    const int s = l & 15;            // sample column (C-col / A-M-row / B-N)
    const int g = l >> 4;            // slot group; C row-quad selector
    const int sb = blockIdx.x * SPW;
    const float L2E2 = 2.8853900817779268f;  // 2*log2(e), folded into W/bias

    // ---- A-frags for tile w: slot (g,j) of chunk c holds
    // k = sigma_c(g,j) = 16*(2c+(j>>2)) + 4g + (j&3).   [HW-verified r3-r5]
    f16x8 a0, a1;
#pragma unroll
    for (int j = 0; j < 8; ++j) {
        const int k0 = 16 * (0 + (j >> 2)) + 4 * g + (j & 3);
        const int k1 = 16 * (2 + (j >> 2)) + 4 * g + (j & 3);
        a0[j] = (_Float16)(W_hh[(16 * w + s) * 64 + k0] * L2E2);
        a1[j] = (_Float16)(W_hh[(16 * w + s) * 64 + k1] * L2E2);
    }

    // ---- per-lane C-slot constants: rows 16w + 4g + r
    float wih[4], bw[4];
#pragma unroll
    for (int r = 0; r < 4; ++r) {
        const int row = 16 * w + 4 * g + r;
        wih[r] = W_ih[row] * L2E2;
        bw[r]  = (b_ih[row] + b_hh[row]) * L2E2;
    }

    // ---- exchange addresses (word granularity) ----
    const int exbase = g * GSTR + s * 10;  // this lane's sample slot
    unsigned* const wrp[2] = {&ex[0][exbase + 2 * w], &ex[1][exbase + 2 * w]};
    const unsigned* const rdp[2] = {&ex[0][exbase], &ex[1][exbase]};

    // ---- state: h[r] = h_state[16w+4g+r] for sample s; h0 = 0.
    float h[4] = {0.0f, 0.0f, 0.0f, 0.0f};

    const float* xs = x + (size_t)(sb + s) * T_;
    float4 xq = *(const float4*)xs;

    for (int t0 = 0; t0 < T_; t0 += 4) {
        const float4 xn = *(const float4*)(xs + (t0 + 4 < T_ ? t0 + 4 : 0));
        const float xa[4] = {xq.x, xq.y, xq.z, xq.w};

#pragma unroll
        for (int j4 = 0; j4 < 4; ++j4) {
            const int buf = j4 & 1;  // t0 is a multiple of 4 -> buf = j4&1

            // --- publish this tile's 4 h values (f16-packed, 8B store) ---
            const u32x2 pk = {pkrtz(h[0], h[1]), pkrtz(h[2], h[3])};
            *(u32x2*)wrp[buf] = pk;

            // --- h-independent affine fills the pre-barrier window ---
            f32x4 ci;
#pragma unroll
            for (int r = 0; r < 4; ++r) ci[r] = fmaf(xa[j4], wih[r], bw[r]);

            lds_barrier();  // all tiles' h_t visible (lgkm-only wait)

            // --- rebuild full B operands: 2x ds_read_b128, lane-aligned ---
            const u32x4 q0 = *(const u32x4*)(rdp[buf] + 0);  // tiles 0,1
            const u32x4 q1 = *(const u32x4*)(rdp[buf] + 4);  // tiles 2,3
            const f16x8 b0 = __builtin_bit_cast(f16x8, q0);  // k =  0..31
            const f16x8 b1 = __builtin_bit_cast(f16x8, q1);  // k = 32..63

            // --- two independent MFMAs (latency-parallel) + f32 combine ---
            const f32x4 zero = {0.0f, 0.0f, 0.0f, 0.0f};
            const f32x4 p0 = __builtin_amdgcn_mfma_f32_16x16x32_f16(a0, b0, ci, 0, 0, 0);
            const f32x4 p1 = __builtin_amdgcn_mfma_f32_16x16x32_f16(a1, b1, zero, 0, 0, 0);
            const f32x4 acc = p0 + p1;

            // --- tanh(pre) = 1 - 2/(exp2(2log2e*pre)+1): 8 trans total ---
#pragma unroll
            for (int r = 0; r < 4; ++r) {
                const float e = __builtin_amdgcn_exp2f(acc[r]);
                h[r] = fmaf(-2.0f, __builtin_amdgcn_rcpf(e + 1.0f), 1.0f);
            }
        }
        xq = xn;
    }

    // ---- FC head: out[s] = sum_row h[row][s] * W_fc[row] + b_fc ----
    float p = 0.0f;
#pragma unroll
    for (int r = 0; r < 4; ++r) p = fmaf(h[r], W_fc[16 * w + 4 * g + r], p);
    p += __shfl_down(p, 32);
    p += __shfl_down(p, 16);
    if (l < 16) fcb[w][l] = p;
    __syncthreads();
    if (tid < 16)
        out[sb + tid] = (fcb[0][tid] + fcb[1][tid]) + (fcb[2][tid] + fcb[3][tid]) + b_fc[0];
}

extern "C" void kernel_launch(void* const* d_in, const int* in_sizes, int n_in,
                              void* d_out, int out_size, void* d_ws, size_t ws_size,
                              hipStream_t stream) {
    const float* x    = (const float*)d_in[0];
    const float* W_ih = (const float*)d_in[1];
    const float* W_hh = (const float*)d_in[2];
    const float* b_ih = (const float*)d_in[3];
    const float* b_hh = (const float*)d_in[4];
    const float* W_fc = (const float*)d_in[5];
    const float* b_fc = (const float*)d_in[6];
    float* out = (float*)d_out;

    rnn_mfma_4w2<<<dim3(B_ / SPW), dim3(256), 0, stream>>>(x, W_ih, W_hh, b_ih, b_hh,
                                                           W_fc, b_fc, out);
}

// Round 7
// 342.989 us; speedup vs baseline: 2.0739x; 2.0739x over previous
//
#include <hip/hip_runtime.h>

#define B_ 2048
#define T_ 2048
#define SPW 16    // samples per block (MFMA N dimension)
#define GSTR 162  // per-g word stride in exchange buf (16 samples * 10 + 2 pad)
#define QT 512    // timesteps per x staging quarter
#define XSTR 516  // f32 stride per sample row in x LDS (pad: 2-way banks, 16B aligned)

typedef _Float16 f16x8 __attribute__((ext_vector_type(8)));
typedef float    f32x4 __attribute__((ext_vector_type(4)));
typedef unsigned u32x2 __attribute__((ext_vector_type(2)));
typedef unsigned u32x4 __attribute__((ext_vector_type(4)));

__device__ __forceinline__ unsigned pkrtz(float lo, float hi) {
    return __builtin_bit_cast(unsigned, __builtin_amdgcn_cvt_pkrtz(lo, hi));
}

// Round 7 = round 5 (380 us, proven) + ONE change: x staged through LDS in
// f32 quarters, so the recurrence loop contains ZERO global memory and the
// per-step __syncthreads vmcnt(0) drain (m97 lesson) has nothing to drain.
// r5/r6 evidence: the in-loop global x prefetch's latency was serialized into
// the recurrence by the barrier's vmcnt drain (~210 cyc/step in r5; worse in
// r6 when hoisted pre-barrier). No inline asm; barriers are plain
// __syncthreads. Per-step arithmetic is bit-identical to r5.
//
// sigma-relabeling (HW-verified r3-r6): sigma_c(g,j) = 16*(2c+(j>>2)) +
// 4g + (j&3); consumer lane (s,g) chunk c reads producer lane (s,g) of waves
// 2c,2c+1 -> lane-aligned f16 exchange, 1 ds_write_b64 + 4 ds_read_b64 per
// step, double-buffered, one barrier per step.
__global__ __launch_bounds__(256)
void rnn_mfma_4w3(
    const float* __restrict__ x, const float* __restrict__ W_ih,
    const float* __restrict__ W_hh, const float* __restrict__ b_ih,
    const float* __restrict__ b_hh, const float* __restrict__ W_fc,
    const float* __restrict__ b_fc, float* __restrict__ out)
{
    __shared__ __align__(16) float xl[SPW * XSTR];      // 33 KB x quarter
    __shared__ __align__(16) unsigned ex[2][4 * GSTR];  // [buf][g][s][10 words]
    __shared__ float fcb[4][SPW];

    const int tid = threadIdx.x;
    const int w = tid >> 6;          // wave index == tile index (rows 16w+..)
    const int l = tid & 63;
    const int s = l & 15;            // sample column (C-col / A-M-row / B-N)
    const int g = l >> 4;            // slot group; C row-quad selector
    const int sb = blockIdx.x * SPW;
    const float L2E2 = 2.8853900817779268f;  // 2*log2(e), folded into W/bias

    // ---- A-frags for tile w: slot (g,j) of chunk c holds
    // k = sigma_c(g,j) = 16*(2c+(j>>2)) + 4g + (j&3).   [HW-verified r3-r6]
    f16x8 a0, a1;
#pragma unroll
    for (int j = 0; j < 8; ++j) {
        const int k0 = 16 * (0 + (j >> 2)) + 4 * g + (j & 3);
        const int k1 = 16 * (2 + (j >> 2)) + 4 * g + (j & 3);
        a0[j] = (_Float16)(W_hh[(16 * w + s) * 64 + k0] * L2E2);
        a1[j] = (_Float16)(W_hh[(16 * w + s) * 64 + k1] * L2E2);
    }

    // ---- per-lane C-slot constants: rows 16w + 4g + r
    float wih[4], bw[4];
#pragma unroll
    for (int r = 0; r < 4; ++r) {
        const int row = 16 * w + 4 * g + r;
        wih[r] = W_ih[row] * L2E2;
        bw[r]  = (b_ih[row] + b_hh[row]) * L2E2;
    }

    // ---- exchange addresses (word granularity) ----
    const int exbase = g * GSTR + s * 10;  // this lane's sample slot
    unsigned* const wr0 = &ex[0][exbase + 2 * w];
    unsigned* const wr1 = &ex[1][exbase + 2 * w];
    const unsigned* const rd0 = &ex[0][exbase];
    const unsigned* const rd1 = &ex[1][exbase];

    // ---- state: h[r] = h_state[16w+4g+r] for sample s; h0 = 0.
    float h[4] = {0.0f, 0.0f, 0.0f, 0.0f};

    const float* xg = x + (size_t)sb * T_;  // this block's 16 sample rows
    const float* const xrow = &xl[s * XSTR];

    for (int q = 0; q < 4; ++q) {
        // ---- stage quarter q: 16 rows x 512 f32, coalesced dwordx4 ----
        __syncthreads();  // all waves done reading the previous quarter
#pragma unroll
        for (int i = 0; i < 2; ++i) {
            const int it  = tid + 256 * i;   // over 16*128 float4 chunks... (2 iters x 256 = 512; need 2048/4=512 chunks? 16 rows * 128 chunks = 2048) 
        }
        for (int it = tid; it < SPW * (QT / 4); it += 256) {
            const int row = it >> 7;         // 128 float4 chunks per row
            const int c4  = it & 127;
            const float4 v =
                *(const float4*)(xg + (size_t)row * T_ + q * QT + 4 * c4);
            *(float4*)&xl[row * XSTR + 4 * c4] = v;
        }
        __syncthreads();  // quarter visible (drains the staging loads once)

        for (int t0 = 0; t0 < QT; t0 += 4) {
            // group's 4 x values from LDS (lane-private, 2-way banks = free)
            const float4 xq = *(const float4*)(xrow + t0);
            const float xa[4] = {xq.x, xq.y, xq.z, xq.w};

#pragma unroll
            for (int j4 = 0; j4 < 4; ++j4) {
                const int buf = j4 & 1;  // t0 multiple of 4 -> buf = j4&1

                // --- publish this tile's 4 h values (f16-packed, 8B) ---
                const u32x2 pk = {pkrtz(h[0], h[1]), pkrtz(h[2], h[3])};
                *(u32x2*)(buf ? wr1 : wr0) = pk;
                __syncthreads();  // all tiles' h_t visible (vmcnt already 0)

                // --- rebuild full B operands (lane-aligned (g,s) slot) ---
                const unsigned* rp = buf ? rd1 : rd0;
                const u32x2 e0 = *(const u32x2*)(rp + 0);  // tile 0 pair
                const u32x2 e1 = *(const u32x2*)(rp + 2);  // tile 1 pair
                const u32x2 e2 = *(const u32x2*)(rp + 4);  // tile 2 pair
                const u32x2 e3 = *(const u32x2*)(rp + 6);  // tile 3 pair
                const u32x4 q0 = {e0.x, e0.y, e1.x, e1.y};
                const u32x4 q1 = {e2.x, e2.y, e3.x, e3.y};
                const f16x8 b0 = __builtin_bit_cast(f16x8, q0);  // k =  0..31
                const f16x8 b1 = __builtin_bit_cast(f16x8, q1);  // k = 32..63

                // --- acc init (bias + x*w_ih as C-in) + 2 chained MFMA ---
                f32x4 ci;
#pragma unroll
                for (int r = 0; r < 4; ++r) ci[r] = fmaf(xa[j4], wih[r], bw[r]);
                const f32x4 p0 =
                    __builtin_amdgcn_mfma_f32_16x16x32_f16(a0, b0, ci, 0, 0, 0);
                const f32x4 acc =
                    __builtin_amdgcn_mfma_f32_16x16x32_f16(a1, b1, p0, 0, 0, 0);

                // --- tanh(pre) = 1 - 2/(exp2(2log2e*pre)+1): 8 trans ---
#pragma unroll
                for (int r = 0; r < 4; ++r) {
                    const float e = __builtin_amdgcn_exp2f(acc[r]);
                    h[r] = fmaf(-2.0f, __builtin_amdgcn_rcpf(e + 1.0f), 1.0f);
                }
            }
        }
    }

    // ---- FC head: out[s] = sum_row h[row][s] * W_fc[row] + b_fc ----
    float p = 0.0f;
#pragma unroll
    for (int r = 0; r < 4; ++r) p = fmaf(h[r], W_fc[16 * w + 4 * g + r], p);
    p += __shfl_down(p, 32);
    p += __shfl_down(p, 16);
    if (l < 16) fcb[w][l] = p;
    __syncthreads();
    if (tid < 16)
        out[sb + tid] = (fcb[0][tid] + fcb[1][tid]) + (fcb[2][tid] + fcb[3][tid]) + b_fc[0];
}

extern "C" void kernel_launch(void* const* d_in, const int* in_sizes, int n_in,
                              void* d_out, int out_size, void* d_ws, size_t ws_size,
                              hipStream_t stream) {
    const float* x    = (const float*)d_in[0];
    const float* W_ih = (const float*)d_in[1];
    const float* W_hh = (const float*)d_in[2];
    const float* b_ih = (const float*)d_in[3];
    const float* b_hh = (const float*)d_in[4];
    const float* W_fc = (const float*)d_in[5];
    const float* b_fc = (const float*)d_in[6];
    float* out = (float*)d_out;

    rnn_mfma_4w3<<<dim3(B_ / SPW), dim3(256), 0, stream>>>(x, W_ih, W_hh, b_ih, b_hh,
                                                           W_fc, b_fc, out);
}